// Round 8
// baseline (98.867 us; speedup 1.0000x reference)
//
#include <hip/hip_runtime.h>
#include <hip/hip_bf16.h>
#include <math.h>

#define BN_EPS 1e-5f

typedef __attribute__((ext_vector_type(8))) short short8;
typedef __attribute__((ext_vector_type(4))) float f32x4;

__device__ __forceinline__ unsigned short bfbits(float f) {
  __hip_bfloat16 h = __float2bfloat16(f);
  return *reinterpret_cast<unsigned short*>(&h);
}
__device__ __forceinline__ float bf2f(unsigned short u) {
  union { unsigned v; float f; } c; c.v = ((unsigned)u) << 16;
  return c.f;
}

// ---------------- Kernel A: prep (blocks 0..15) + pool (blocks 16..2063) ----
// pool: one wave per (b,c) plane, no LDS, no syncthreads.
__global__ __launch_bounds__(256) void prep_pool_kernel(
    const float* __restrict__ x, float* __restrict__ pooled,
    const float* __restrict__ fc3_w,
    const float* __restrict__ g3, const float* __restrict__ b3,
    const float* __restrict__ m3, const float* __restrict__ v3,
    const float* __restrict__ c1w,
    const float* __restrict__ g1, const float* __restrict__ b1,
    const float* __restrict__ m1, const float* __restrict__ v1,
    const float* __restrict__ c3w,
    const float* __restrict__ gk, const float* __restrict__ bk,
    const float* __restrict__ mk, const float* __restrict__ vk,
    unsigned short* __restrict__ ahi, unsigned short* __restrict__ alo,
    float* __restrict__ totb) {
  int bid = blockIdx.x;
  int tid = threadIdx.x;
  if (bid < 16) {
    int s = bid >> 2;
    int o = (bid & 3) * 16 + (tid >> 4);
    int kc = (tid & 15) * 4;
    float sc3 = g3[s] * rsqrtf(v3[s] + BN_EPS);
    float sc1 = g1[s] * rsqrtf(v1[s] + BN_EPS);
    float sck = gk[s] * rsqrtf(vk[s] + BN_EPS);
    float c0 = sc1 * c1w[s] + sck * c3w[s * 9 + 4];
    int oh = o >> 3, ow = o & 7;
    unsigned short H[4], L[4];
#pragma unroll
    for (int j = 0; j < 4; ++j) {
      int k = kc + j;
      int kh = k >> 3, kw = k & 7;
      float a = sc3 * fc3_w[(s * 64 + o) * 64 + k];
      int dy = kh - oh, dx = kw - ow;
      if (dy >= -1 && dy <= 1 && dx >= -1 && dx <= 1)
        a += (dy == 0 && dx == 0) ? c0 : sck * c3w[s * 9 + (dy + 1) * 3 + (dx + 1)];
      unsigned short h = bfbits(a);
      H[j] = h;
      L[j] = bfbits(a - bf2f(h));
    }
    size_t base = (size_t)(s * 64 + o) * 64 + kc;
    *(ushort4*)(ahi + base) = make_ushort4(H[0], H[1], H[2], H[3]);
    *(ushort4*)(alo + base) = make_ushort4(L[0], L[1], L[2], L[3]);
    if (bid == 0 && tid < 4) {
      int ss = tid;
      float s3 = g3[ss] * rsqrtf(v3[ss] + BN_EPS);
      float s1 = g1[ss] * rsqrtf(v1[ss] + BN_EPS);
      float sk = gk[ss] * rsqrtf(vk[ss] + BN_EPS);
      totb[ss] = (b3[ss] - m3[ss] * s3) + (b1[ss] - m1[ss] * s1) + (bk[ss] - mk[ss] * sk);
    }
    return;
  }
  // pool: wave w of this block reduces plane (bid-16)*4 + w
  int w = tid >> 6, lane = tid & 63;
  int bc = (bid - 16) * 4 + w;
  const f32x4* xp = (const f32x4*)(x + (size_t)bc * 4096);
  float ssum = 0.f;
#pragma unroll
  for (int i = 0; i < 16; ++i) {
    f32x4 v = xp[i * 64 + lane];
    ssum += (v.x + v.y) + (v.z + v.w);
  }
#pragma unroll
  for (int m = 32; m >= 1; m >>= 1) ssum += __shfl_xor(ssum, m, 64);
  if (lane == 0) pooled[bc] = ssum * (1.f / 4096.f);
}

// ---------------- Kernel B: gate MLP ----------------
__global__ __launch_bounds__(256) void gate_kernel(const float* __restrict__ pooled,
                                                   const float* __restrict__ fc1_w,
                                                   const float* __restrict__ fc1_b,
                                                   const float* __restrict__ fc2_w,
                                                   const float* __restrict__ fc2_b,
                                                   float* __restrict__ gate) {
  int b = blockIdx.x;
  int tid = threadIdx.x;
  __shared__ float p[256];
  __shared__ float hbuf[64];
  p[tid] = pooled[b * 256 + tid];
  __syncthreads();
  if (tid < 64) {
    float a = fc1_b[tid];
    const float* wr = fc1_w + tid * 256;
#pragma unroll 8
    for (int c = 0; c < 256; ++c) a += p[c] * wr[c];
    hbuf[tid] = fmaxf(a, 0.f);
  }
  __syncthreads();
  float g = fc2_b[tid];
  const float* w2 = fc2_w + tid * 64;
#pragma unroll 8
  for (int j = 0; j < 64; ++j) g += hbuf[j] * w2[j];
  gate[b * 256 + tid] = 1.f / (1.f + expf(-g));
}

// ---------------- Kernel C: main — fine-split GEMM -----------------------
// Grid 8192 = (b, hpi, cgh, s); s block-uniform. Block = 4 waves =
// (o-half x col-half). Per-wave: A 32, acc 16, q 32 VGPR; all 8 B-loads
// issued up front (single exposed L3 latency). B dup across o-halves is
// block-local (16 KB) -> L1-hit.
__global__ __launch_bounds__(256, 4) void main_kernel(
    const float* __restrict__ x,
    const unsigned short* __restrict__ ahi, const unsigned short* __restrict__ alo,
    const float* __restrict__ totb, const float* __restrict__ gate,
    float* __restrict__ out) {
  int bid = blockIdx.x;
  int s   = bid & 3;
  int cgh = (bid >> 2) & 7;
  int hpi = (bid >> 5) & 7;
  int b   = bid >> 8;
  int tid = threadIdx.x;
  int wv  = tid >> 6;
  int colhalf = __builtin_amdgcn_readfirstlane(wv & 1);
  int half    = __builtin_amdgcn_readfirstlane(wv >> 1);
  int r16 = tid & 15;
  int g   = (tid >> 4) & 3;

  // ---- all 8 B-loads up front ----
  f32x4 q[2][2][2];  // [kt][nt][quad]
  int c_in = (cgh * 8 + (r16 & 7)) * 4 + s;
  const float* xbase = x + (size_t)(b * 256 + c_in) * 4096;
#pragma unroll
  for (int kt = 0; kt < 2; ++kt)
#pragma unroll
    for (int nt = 0; nt < 2; ++nt) {
      int wpi = (colhalf * 2 + nt) * 2 + (r16 >> 3);
      const float* bp = xbase + (hpi * 8 + kt * 4 + g) * 64 + wpi * 8;
      q[kt][nt][0] = *(const f32x4*)bp;
      q[kt][nt][1] = *(const f32x4*)(bp + 4);
    }

  // ---- A fragments (L2-resident) ----
  short8 Ah[2][2], Al[2][2];  // [kt][oti]
#pragma unroll
  for (int oti = 0; oti < 2; ++oti)
#pragma unroll
    for (int kt = 0; kt < 2; ++kt) {
      size_t off = (size_t)(s * 64 + (half * 2 + oti) * 16 + r16) * 64 + kt * 32 + g * 8;
      Ah[kt][oti] = *(const short8*)(ahi + off);
      Al[kt][oti] = *(const short8*)(alo + off);
    }

  // ---- gate + bias (early issue) ----
  float gmul[2];
#pragma unroll
  for (int nt = 0; nt < 2; ++nt) {
    int n2 = (colhalf * 2 + nt) * 16 + r16;
    gmul[nt] = gate[b * 256 + hpi * 32 + (n2 >> 3) * 4 + s];
  }
  float tb = totb[s];

  // ---- convert + MFMA ----
  f32x4 acc[2][2];
#pragma unroll
  for (int i = 0; i < 2; ++i)
#pragma unroll
    for (int j = 0; j < 2; ++j) acc[i][j] = f32x4{0.f, 0.f, 0.f, 0.f};

#pragma unroll
  for (int kt = 0; kt < 2; ++kt)
#pragma unroll
    for (int nt = 0; nt < 2; ++nt) {
      float fv[8] = {q[kt][nt][0].x, q[kt][nt][0].y, q[kt][nt][0].z, q[kt][nt][0].w,
                     q[kt][nt][1].x, q[kt][nt][1].y, q[kt][nt][1].z, q[kt][nt][1].w};
      union { unsigned short u16[8]; short8 v; } BH, BL;
#pragma unroll
      for (int j = 0; j < 8; ++j) {
        unsigned short h = bfbits(fv[j]);
        BH.u16[j] = h;
        BL.u16[j] = bfbits(fv[j] - bf2f(h));
      }
#pragma unroll
      for (int oti = 0; oti < 2; ++oti) {
        acc[oti][nt] = __builtin_amdgcn_mfma_f32_16x16x32_bf16(Ah[kt][oti], BH.v, acc[oti][nt], 0, 0, 0);
        acc[oti][nt] = __builtin_amdgcn_mfma_f32_16x16x32_bf16(Ah[kt][oti], BL.v, acc[oti][nt], 0, 0, 0);
        acc[oti][nt] = __builtin_amdgcn_mfma_f32_16x16x32_bf16(Al[kt][oti], BH.v, acc[oti][nt], 0, 0, 0);
      }
    }

  // ---- epilogue: direct nontemporal stores ----
#pragma unroll
  for (int nt = 0; nt < 2; ++nt) {
    int n2 = (colhalf * 2 + nt) * 16 + r16;
    int c_out = hpi * 32 + (n2 >> 3) * 4 + s;
    float gm = gmul[nt];
    float* outb = out + (size_t)(b * 256 + c_out) * 4096 + cgh * 8 * 64 + (n2 & 7) * 8;
#pragma unroll
    for (int oti = 0; oti < 2; ++oti) {
      f32x4 a = acc[oti][nt];
      int hh = (half * 2 + oti) * 2 + (g >> 1);
      int wo = (g & 1) * 4;
      f32x4 o4 = {(a.x + tb) * gm, (a.y + tb) * gm,
                  (a.z + tb) * gm, (a.w + tb) * gm};
      __builtin_nontemporal_store(o4, (f32x4*)(outb + hh * 64 + wo));
    }
  }
}

extern "C" void kernel_launch(void* const* d_in, const int* in_sizes, int n_in,
                              void* d_out, int out_size, void* d_ws, size_t ws_size,
                              hipStream_t stream) {
  const float* x     = (const float*)d_in[0];
  const float* fc1_w = (const float*)d_in[1];
  const float* fc1_b = (const float*)d_in[2];
  const float* fc2_w = (const float*)d_in[3];
  const float* fc2_b = (const float*)d_in[4];
  const float* fc3_w = (const float*)d_in[5];
  const float* g3  = (const float*)d_in[6];
  const float* b3  = (const float*)d_in[7];
  const float* m3  = (const float*)d_in[8];
  const float* v3  = (const float*)d_in[9];
  const float* c1w = (const float*)d_in[10];
  const float* g1  = (const float*)d_in[11];
  const float* b1  = (const float*)d_in[12];
  const float* m1  = (const float*)d_in[13];
  const float* v1  = (const float*)d_in[14];
  const float* c3w = (const float*)d_in[15];
  const float* gk  = (const float*)d_in[16];
  const float* bk  = (const float*)d_in[17];
  const float* mk  = (const float*)d_in[18];
  const float* vk  = (const float*)d_in[19];
  float* out = (float*)d_out;

  float* pooled = (float*)d_ws;
  float* gate   = pooled + 8192;
  unsigned short* ahi = (unsigned short*)(gate + 8192);
  unsigned short* alo = ahi + 16384;
  float* totb   = (float*)(alo + 16384);

  prep_pool_kernel<<<2064, 256, 0, stream>>>(x, pooled, fc3_w, g3, b3, m3, v3,
                                             c1w, g1, b1, m1, v1, c3w, gk, bk,
                                             mk, vk, ahi, alo, totb);
  gate_kernel<<<32, 256, 0, stream>>>(pooled, fc1_w, fc1_b, fc2_w, fc2_b, gate);
  main_kernel<<<8192, 256, 0, stream>>>(x, ahi, alo, totb, gate, out);
}